// Round 9
// baseline (125.507 us; speedup 1.0000x reference)
//
#include <hip/hip_runtime.h>
#include <stdint.h>

typedef unsigned short u16;
typedef unsigned int u32;
typedef __attribute__((ext_vector_type(4))) float f32x4;
typedef __attribute__((ext_vector_type(16))) float f32x16;
typedef __attribute__((ext_vector_type(8))) __bf16 bf16x8;
typedef __attribute__((ext_vector_type(8))) u16 u16x8;

constexpr int NB = 2, NT = 2048, NTC = 2048, NE = 1024, NH = 16, ND = 64;
constexpr int MTOK = NB * NT;   // 4096 tokens
constexpr int KDIM = NE;        // 1024
// 1024^-0.25 * sqrt(log2(e)) folded into Wq,Wk casts -> scores in exp2 domain
constexpr float QK_SCALE = (float)(0.17677669529663687 * 1.2011224087864498);
constexpr float FIXED_M = 24.0f;  // fixed softmax offset (exp2 domain)

__device__ __forceinline__ u16 f2bf(float f) {
  union { float f; uint32_t u; } v; v.f = f;
  uint32_t r = v.u + 0x7FFFu + ((v.u >> 16) & 1u);  // RNE
  return (u16)(r >> 16);
}

__device__ __forceinline__ float fexp2(float x) {
#if __has_builtin(__builtin_amdgcn_exp2f)
  return __builtin_amdgcn_exp2f(x);
#else
  return exp2f(x);
#endif
}

__device__ __forceinline__ u32 cvtpk(float lo, float hi) {
  u32 r;
  asm("v_cvt_pk_bf16_f32 %0, %1, %2" : "=v"(r) : "v"(lo), "v"(hi));
  return r;
}

__device__ __forceinline__ void plswap(u32& a, u32& b) {
  asm("v_permlane32_swap_b32 %0, %1" : "+v"(a), "+v"(b));
}

__device__ __forceinline__ void gload16(const void* g, void* lds) {
  __builtin_amdgcn_global_load_lds(
      (const __attribute__((address_space(1))) unsigned int*)g,
      (__attribute__((address_space(3))) unsigned int*)lds, 16, 0, 0);
}

__device__ __forceinline__ f32x16 mfma32x32(bf16x8 a, bf16x8 b, f32x16 c) {
  return __builtin_amdgcn_mfma_f32_32x32x16_bf16(a, b, c, 0, 0, 0);
}

__device__ __forceinline__ u16x8 cast8(const float4* p, float scale) {
  float4 a = p[0], b = p[1];
  u16x8 r;
  r[0] = f2bf(a.x * scale); r[1] = f2bf(a.y * scale);
  r[2] = f2bf(a.z * scale); r[3] = f2bf(a.w * scale);
  r[4] = f2bf(b.x * scale); r[5] = f2bf(b.y * scale);
  r[6] = f2bf(b.z * scale); r[7] = f2bf(b.w * scale);
  return r;
}

// ======== granule-transposed layout: bf16 matrix [R rows][1024 cols] stored as
// element (r,c) -> ((c>>3)*R + r)*8 + (c&7).  16-B granule = 8 k's of one row. ========

// ---------------- one fused cast launch (granule-transposed outputs) ----------------
// thread handles one (row, kg-pair): reads 64 B (full line), writes 2 coalesced granules.
__global__ void cast_all(const float* __restrict__ x, const float* __restrict__ ctx,
                         const float* __restrict__ Wq, const float* __restrict__ Wk,
                         const float* __restrict__ Wv, const float* __restrict__ Wo,
                         u16* __restrict__ xb, u16* __restrict__ cb,
                         u16* __restrict__ wqb, u16* __restrict__ wkvb,
                         u16* __restrict__ wob) {
  int i = blockIdx.x * blockDim.x + threadIdx.x;   // 0..786431
  const float* src; u16* dst; int n, kgp, Rr, noff = 0; float scale = 1.0f;
  int region = i >> 18;
  if (region == 0) { int j = i; n = j & 4095; kgp = j >> 12; src = x; dst = xb; Rr = 4096; }
  else if (region == 1) { int j = i & 262143; n = j & 4095; kgp = j >> 12; src = ctx; dst = cb; Rr = 4096; }
  else {
    int j = i & 262143;
    int wsel = j >> 16, jj = j & 65535;
    n = jj & 1023; kgp = jj >> 10;
    src = (wsel == 0) ? Wq : (wsel == 1) ? Wk : (wsel == 2) ? Wv : Wo;
    scale = (wsel < 2) ? QK_SCALE : 1.0f;
    if (wsel == 0) { dst = wqb; Rr = 1024; }
    else if (wsel == 3) { dst = wob; Rr = 1024; }
    else { dst = wkvb; Rr = 2048; noff = (wsel == 2) ? 1024 : 0; }
  }
  const float4* p = (const float4*)(src + (size_t)n * 1024 + kgp * 16);
  u16x8 g0 = cast8(p, scale);
  u16x8 g1 = cast8(p + 2, scale);
  int kg = kgp * 2;
  *(u16x8*)(dst + ((size_t)kg * Rr + n + noff) * 8) = g0;
  *(u16x8*)(dst + ((size_t)(kg + 1) * Rr + n + noff) * 8) = g1;
}

// ---------------- shared 128x128 GEMM loop (32x32x16 MFMA) ----------------
// LDS tiles stored [part(8)][row(128)] granules -> staging linear-coalesced,
// frag reads = 32 consecutive granules (conflict-free). m97-style 2-barrier loop.
__device__ __forceinline__ void gemm128_loop(const char* Ag, const char* Bg,
                                             int RrA, int RrB,
                                             u16* Al, u16* Bl, int tid,
                                             f32x16 (&acc)[2][2]) {
  const int w = tid >> 6, l = tid & 63;
  const int l31 = l & 31, hi = l >> 5;
  const int wm = w >> 1, wn = w & 1;

  for (int it = 0; it < 16; ++it) {
#pragma unroll
    for (int s = 0; s < 4; ++s) {
      int g = (w * 4 + s) * 64 + l;          // granule id 0..1023
      int p = g >> 7, rr = g & 127;
      gload16(Ag + ((size_t)(it * 8 + p) * RrA + rr) * 16, (char*)Al + (w * 4 + s) * 1024);
      gload16(Bg + ((size_t)(it * 8 + p) * RrB + rr) * 16, (char*)Bl + (w * 4 + s) * 1024);
    }
    __syncthreads();
#pragma unroll
    for (int kc = 0; kc < 4; ++kc) {
      const int p = kc * 2 + hi;
      bf16x8 af0 = *(const bf16x8*)((const char*)Al + (size_t)(p * 128 + wm * 64 + l31) * 16);
      bf16x8 af1 = *(const bf16x8*)((const char*)Al + (size_t)(p * 128 + wm * 64 + 32 + l31) * 16);
      bf16x8 bf0 = *(const bf16x8*)((const char*)Bl + (size_t)(p * 128 + wn * 64 + l31) * 16);
      bf16x8 bf1 = *(const bf16x8*)((const char*)Bl + (size_t)(p * 128 + wn * 64 + 32 + l31) * 16);
      acc[0][0] = mfma32x32(af0, bf0, acc[0][0]);
      acc[0][1] = mfma32x32(af0, bf1, acc[0][1]);
      acc[1][0] = mfma32x32(af1, bf0, acc[1][0]);
      acc[1][1] = mfma32x32(af1, bf1, acc[1][1]);
    }
    __syncthreads();
  }
}

// ---------------- fused Q + KV projection GEMM ----------------
// logical blocks [0,256): Q = xb @ Wq^T; [256,768): KV = cb @ [Wk;Wv]^T
__global__ __launch_bounds__(256)
void gemm_qkv(const u16* __restrict__ xb, const u16* __restrict__ cb,
              const u16* __restrict__ wqb, const u16* __restrict__ wkvb,
              u16* __restrict__ Qb, u16* __restrict__ KVb) {
  __shared__ __align__(16) u16 Al[1024 * 8];
  __shared__ __align__(16) u16 Bl[1024 * 8];
  const int tid = threadIdx.x, w = tid >> 6, l = tid & 63;
  const int l31 = l & 31, hi = l >> 5;
  const int wm = w >> 1, wn = w & 1;

  int bid = blockIdx.x;
  bid = (bid & 7) * 96 + (bid >> 3);     // bijective: 768 = 8*96
  const bool isQ = bid < 256;
  const u16* A; const u16* Bm; int mbase, nbase, RrB;
  if (isQ) { A = xb; Bm = wqb; RrB = 1024; nbase = (bid & 7) * 128; mbase = (bid >> 3) * 128; }
  else { int b2 = bid - 256; A = cb; Bm = wkvb; RrB = 2048;
         nbase = (b2 & 15) * 128; mbase = (b2 >> 4) * 128; }

  f32x16 acc[2][2] = {};
  gemm128_loop((const char*)A + (size_t)mbase * 16,
               (const char*)Bm + (size_t)nbase * 16,
               4096, RrB, Al, Bl, tid, acc);

#pragma unroll
  for (int mt = 0; mt < 2; ++mt) {
#pragma unroll
    for (int nt = 0; nt < 2; ++nt) {
      int n = nbase + wn * 64 + nt * 32 + l31;
#pragma unroll
      for (int r = 0; r < 16; ++r) {
        int crow = (r & 3) + 8 * (r >> 2) + 4 * hi;
        int m = mbase + wm * 64 + mt * 32 + crow;
        float v = acc[mt][nt][r];
        if (isQ) {
          int b = m >> 11, t = m & (NT - 1), h = n >> 6, d = n & (ND - 1);
          Qb[((size_t)(b * NH + h) * NT + t) * ND + d] = f2bf(v);
        } else {
          int b = m >> 11, tc = m & (NTC - 1);
          int h = (n >> 6) & 15, d = n & (ND - 1);
          size_t base = ((size_t)((b * NH + h) * 32 + (tc >> 6))) * 4096;
          if (n < 1024) {  // K layout: [dpart][key][d&7]
            size_t idx = base + (size_t)(d >> 3) * 512 + (size_t)(tc & 63) * 8 + (d & 7);
            KVb[idx] = f2bf(v);
          } else {         // V layout: [keypart][d][key&7], V buffer at +4M elems
            size_t idx = base + (size_t)((tc & 63) >> 3) * 512 + (size_t)d * 8 + (tc & 7);
            KVb[4194304 + idx] = f2bf(v);
          }
        }
      }
    }
  }
}

// ---------------- out projection GEMM (f32 out + bias) ----------------
__global__ __launch_bounds__(256)
void gemm_out(const u16* __restrict__ A, const u16* __restrict__ Bm,
              float* __restrict__ Cout, const float* __restrict__ bias) {
  __shared__ __align__(16) u16 Al[1024 * 8];
  __shared__ __align__(16) u16 Bl[1024 * 8];
  const int tid = threadIdx.x, w = tid >> 6, l = tid & 63;
  const int l31 = l & 31, hi = l >> 5;
  const int wm = w >> 1, wn = w & 1;

  int bid = blockIdx.x;
  bid = (bid & 7) * 32 + (bid >> 3);     // bijective: 256 = 8*32
  const int mbase = (bid >> 3) * 128, nbase = (bid & 7) * 128;

  f32x16 acc[2][2] = {};
  gemm128_loop((const char*)A + (size_t)mbase * 16,
               (const char*)Bm + (size_t)nbase * 16,
               4096, 1024, Al, Bl, tid, acc);

#pragma unroll
  for (int mt = 0; mt < 2; ++mt) {
#pragma unroll
    for (int nt = 0; nt < 2; ++nt) {
      int n = nbase + wn * 64 + nt * 32 + l31;
      float bv = bias[n];
#pragma unroll
      for (int r = 0; r < 16; ++r) {
        int crow = (r & 3) + 8 * (r >> 2) + 4 * hi;
        int m = mbase + wm * 64 + mt * 32 + crow;
        Cout[(size_t)m * NE + n] = acc[mt][nt][r] + bv;
      }
    }
  }
}

// ---------------- flash attention (R5 core; Ob write granule-transposed) ----------------
__global__ __launch_bounds__(128, 2)
void attn_fwd(const u16* __restrict__ Q, const u16* __restrict__ K,
              const u16* __restrict__ Vt, u16* __restrict__ O) {
  __shared__ float Ol[64 * 64];
  __shared__ float Ll[64];
  const int tid = threadIdx.x, wid = tid >> 6, l = tid & 63;
  const int l31 = l & 31, hi = l >> 5;

  int n = blockIdx.x;
  int work = (n & 7) * 128 + (n >> 3);
  const int bh = work >> 5, qx = work & 31;
  const int b = bh >> 4, h = bh & 15;
  const int qbase = qx * 64;

  const char* Kb = (const char*)(K + (size_t)bh * 32 * 4096);
  const char* Vb = (const char*)(Vt + (size_t)bh * 32 * 4096);
  const u16* Qb = Q + (size_t)bh * NT * ND;

  auto kaddr = [&](int t32, int kc) {
    return Kb + (size_t)(t32 >> 1) * 8192 + (size_t)(kc * 2 + hi) * 1024
              + (size_t)((t32 & 1) * 32 + l31) * 16;
  };
  auto vaddr = [&](int t32, int j) {  // j = ks*2 + nt
    return Vb + (size_t)(t32 >> 1) * 8192
              + (size_t)((t32 & 1) * 4 + (j >> 1) * 2 + hi) * 1024
              + (size_t)((j & 1) * 32 + l31) * 16;
  };

  bf16x8 qf[2][4];
#pragma unroll
  for (int qt = 0; qt < 2; ++qt)
#pragma unroll
    for (int kc = 0; kc < 4; ++kc)
      qf[qt][kc] = *(const bf16x8*)(Qb + (size_t)(qbase + qt * 32 + l31) * ND + kc * 16 + hi * 8);

  f32x16 oacc[2][2] = {};
  f32x16 lacc[2] = {};
  f32x16 minit;
#pragma unroll
  for (int r = 0; r < 16; ++r) minit[r] = -FIXED_M;

  const int tbase = wid * 32;

  bf16x8 kfA[4], kfB[4], vf[4];
#pragma unroll
  for (int kc = 0; kc < 4; ++kc) kfA[kc] = *(const bf16x8*)kaddr(tbase, kc);

  for (int it2 = 0; it2 < 16; ++it2) {
    const int tA = tbase + it2 * 2, tB = tA + 1;

    // ---- iter A (uses kfA, prefetches kfB = tB) ----
#pragma unroll
    for (int j = 0; j < 4; ++j) vf[j] = *(const bf16x8*)vaddr(tA, j);
#pragma unroll
    for (int kc = 0; kc < 4; ++kc) kfB[kc] = *(const bf16x8*)kaddr(tB, kc);
#pragma unroll
    for (int qt = 0; qt < 2; ++qt) {
      f32x16 sv = minit;
#pragma unroll
      for (int kc = 0; kc < 4; ++kc) sv = mfma32x32(kfA[kc], qf[qt][kc], sv);
#pragma unroll
      for (int r = 0; r < 16; ++r) { sv[r] = fexp2(sv[r]); lacc[qt][r] += sv[r]; }
      bf16x8 pa0, pa1;
      {
        u32 a1 = cvtpk(sv[0], sv[1]), b1 = cvtpk(sv[4], sv[5]);
        u32 a2 = cvtpk(sv[2], sv[3]), b2 = cvtpk(sv[6], sv[7]);
        plswap(a1, b1); plswap(a2, b2);
        u32 a3 = cvtpk(sv[8], sv[9]), b3 = cvtpk(sv[12], sv[13]);
        u32 a4 = cvtpk(sv[10], sv[11]), b4 = cvtpk(sv[14], sv[15]);
        plswap(a3, b3); plswap(a4, b4);
        union { u32 u[4]; bf16x8 v; } ua, ub;
        ua.u[0] = a1; ua.u[1] = a2; ua.u[2] = b1; ua.u[3] = b2;
        ub.u[0] = a3; ub.u[1] = a4; ub.u[2] = b3; ub.u[3] = b4;
        pa0 = ua.v; pa1 = ub.v;
      }
      oacc[qt][0] = mfma32x32(pa0, vf[0], oacc[qt][0]);
      oacc[qt][1] = mfma32x32(pa0, vf[1], oacc[qt][1]);
      oacc[qt][0] = mfma32x32(pa1, vf[2], oacc[qt][0]);
      oacc[qt][1] = mfma32x32(pa1, vf[3], oacc[qt][1]);
    }

    // ---- iter B (uses kfB, prefetches kfA = tB+1) ----
#pragma unroll
    for (int j = 0; j < 4; ++j) vf[j] = *(const bf16x8*)vaddr(tB, j);
#pragma unroll
    for (int kc = 0; kc < 4; ++kc) kfA[kc] = *(const bf16x8*)kaddr(tB + 1, kc);
#pragma unroll
    for (int qt = 0; qt < 2; ++qt) {
      f32x16 sv = minit;
#pragma unroll
      for (int kc = 0; kc < 4; ++kc) sv = mfma32x32(kfB[kc], qf[qt][kc], sv);
#pragma unroll
      for (int r = 0; r < 16; ++r) { sv[r] = fexp2(sv[r]); lacc[qt][r] += sv[r]; }
      bf16x8 pa0, pa1;
      {
        u32 a1 = cvtpk(sv[0], sv[1]), b1 = cvtpk(sv[4], sv[5]);
        u32 a2 = cvtpk(sv[2], sv[3]), b2 = cvtpk(sv[6], sv[7]);
        plswap(a1, b1); plswap(a2, b2);
        u32 a3 = cvtpk(sv[8], sv[9]), b3 = cvtpk(sv[12], sv[13]);
        u32 a4 = cvtpk(sv[10], sv[11]), b4 = cvtpk(sv[14], sv[15]);
        plswap(a3, b3); plswap(a4, b4);
        union { u32 u[4]; bf16x8 v; } ua, ub;
        ua.u[0] = a1; ua.u[1] = a2; ua.u[2] = b1; ua.u[3] = b2;
        ub.u[0] = a3; ub.u[1] = a4; ub.u[2] = b3; ub.u[3] = b4;
        pa0 = ua.v; pa1 = ub.v;
      }
      oacc[qt][0] = mfma32x32(pa0, vf[0], oacc[qt][0]);
      oacc[qt][1] = mfma32x32(pa0, vf[1], oacc[qt][1]);
      oacc[qt][0] = mfma32x32(pa1, vf[2], oacc[qt][0]);
      oacc[qt][1] = mfma32x32(pa1, vf[3], oacc[qt][1]);
    }
  }

  float lsum[2];
#pragma unroll
  for (int qt = 0; qt < 2; ++qt) {
    f32x16 t = lacc[qt];
#pragma unroll
    for (int s = 8; s >= 1; s >>= 1)
#pragma unroll
      for (int r = 0; r < s; ++r) t[r] += t[r + s];
    lsum[qt] = t[0] + __shfl_xor(t[0], 32);
  }

  if (wid == 1) {
#pragma unroll
    for (int qt = 0; qt < 2; ++qt) {
#pragma unroll
      for (int r = 0; r < 16; ++r) {
        int crow = (r & 3) + 8 * (r >> 2) + 4 * hi;
        Ol[(qt * 32 + crow) * 64 + l31] = oacc[qt][0][r];
        Ol[(qt * 32 + crow) * 64 + 32 + l31] = oacc[qt][1][r];
      }
      if (!hi) Ll[qt * 32 + l31] = lsum[qt];
    }
  }
  __syncthreads();
  if (wid == 0) {
#pragma unroll
    for (int qt = 0; qt < 2; ++qt) {
      float inv = 1.0f / (lsum[qt] + Ll[qt * 32 + l31]);
#pragma unroll
      for (int r = 0; r < 16; ++r) {
        int crow = (r & 3) + 8 * (r >> 2) + 4 * hi;
        float ir = __shfl(inv, crow);
        int t = qbase + qt * 32 + crow;
        int token = b * NT + t;
        float v0 = (oacc[qt][0][r] + Ol[(qt * 32 + crow) * 64 + l31]) * ir;
        float v1 = (oacc[qt][1][r] + Ol[(qt * 32 + crow) * 64 + 32 + l31]) * ir;
        // granule-transposed O: elem (token, e) -> ((e>>3)*4096 + token)*8 + (e&7)
        size_t i0 = ((size_t)(h * 8 + (l31 >> 3)) * 4096 + token) * 8 + (l31 & 7);
        size_t i1 = ((size_t)(h * 8 + 4 + (l31 >> 3)) * 4096 + token) * 8 + (l31 & 7);
        O[i0] = f2bf(v0);
        O[i1] = f2bf(v1);
      }
    }
  }
}

// ---------------- launch ----------------
extern "C" void kernel_launch(void* const* d_in, const int* in_sizes, int n_in,
                              void* d_out, int out_size, void* d_ws, size_t ws_size,
                              hipStream_t stream) {
  const float* x   = (const float*)d_in[0];
  const float* ctx = (const float*)d_in[1];
  const float* Wq  = (const float*)d_in[2];
  const float* Wk  = (const float*)d_in[3];
  const float* Wv  = (const float*)d_in[4];
  const float* Wo  = (const float*)d_in[5];
  const float* bo  = (const float*)d_in[6];
  float* out = (float*)d_out;
  char* ws = (char*)d_ws;

  u16* xb  = (u16*)(ws);                       // 8 MB  x   granule-transposed [128kg][4096]
  u16* cb  = (u16*)(ws + (8u  << 20));         // 8 MB  ctx granule-transposed
  u16* wqb = (u16*)(ws + (16u << 20));         // 2 MB  Wq*s granule-transposed [128kg][1024]
  u16* wkvb= (u16*)(ws + (18u << 20));         // 4 MB  [Wk*s;Wv] granule-transposed [128kg][2048]
  u16* wob = (u16*)(ws + (22u << 20));         // 2 MB  Wo granule-transposed
  u16* Qb  = (u16*)(ws + (24u << 20));         // 8 MB  Q  [bh][t][64]
  u16* Kb  = (u16*)(ws + (32u << 20));         // 8 MB  K  tiled-transposed (V contiguous)
  u16* Vtb = (u16*)(ws + (40u << 20));         // 8 MB  V  tiled-transposed
  u16* Ob  = (u16*)(ws + (48u << 20));         // 8 MB  O  granule-transposed [128kg][4096]

  cast_all<<<3072, 256, 0, stream>>>(x, ctx, Wq, Wk, Wv, Wo, xb, cb, wqb, wkvb, wob);
  gemm_qkv<<<768, 256, 0, stream>>>(xb, cb, wqb, wkvb, Qb, Kb);
  attn_fwd<<<1024, 128, 0, stream>>>(Qb, Kb, Vtb, Ob);
  gemm_out<<<256, 256, 0, stream>>>(Ob, wob, out, bo);
}

// Round 10
// 112.283 us; speedup vs baseline: 1.1178x; 1.1178x over previous
//
#include <hip/hip_runtime.h>
#include <stdint.h>

typedef unsigned short u16;
typedef unsigned int u32;
typedef __attribute__((ext_vector_type(4))) float f32x4;
typedef __attribute__((ext_vector_type(16))) float f32x16;
typedef __attribute__((ext_vector_type(8))) __bf16 bf16x8;
typedef __attribute__((ext_vector_type(8))) u16 u16x8;

constexpr int NB = 2, NT = 2048, NTC = 2048, NE = 1024, NH = 16, ND = 64;
constexpr int MTOK = NB * NT;   // 4096 tokens
constexpr int KDIM = NE;        // 1024
// 1024^-0.25 * sqrt(log2(e)) folded into Wq,Wk casts -> scores in exp2 domain
constexpr float QK_SCALE = (float)(0.17677669529663687 * 1.2011224087864498);
constexpr float FIXED_M = 24.0f;  // fixed softmax offset (exp2 domain)

__device__ __forceinline__ u16 f2bf(float f) {
  union { float f; uint32_t u; } v; v.f = f;
  uint32_t r = v.u + 0x7FFFu + ((v.u >> 16) & 1u);  // RNE
  return (u16)(r >> 16);
}

__device__ __forceinline__ float fexp2(float x) {
#if __has_builtin(__builtin_amdgcn_exp2f)
  return __builtin_amdgcn_exp2f(x);
#else
  return exp2f(x);
#endif
}

__device__ __forceinline__ u32 cvtpk(float lo, float hi) {
  u32 r;
  asm("v_cvt_pk_bf16_f32 %0, %1, %2" : "=v"(r) : "v"(lo), "v"(hi));
  return r;
}

__device__ __forceinline__ void plswap(u32& a, u32& b) {
  asm("v_permlane32_swap_b32 %0, %1" : "+v"(a), "+v"(b));
}

__device__ __forceinline__ void gload16(const void* g, void* lds) {
  __builtin_amdgcn_global_load_lds(
      (const __attribute__((address_space(1))) unsigned int*)g,
      (__attribute__((address_space(3))) unsigned int*)lds, 16, 0, 0);
}

__device__ __forceinline__ f32x4 mfma16x16(bf16x8 a, bf16x8 b, f32x4 c) {
  return __builtin_amdgcn_mfma_f32_16x16x32_bf16(a, b, c, 0, 0, 0);
}
__device__ __forceinline__ f32x16 mfma32x32(bf16x8 a, bf16x8 b, f32x16 c) {
  return __builtin_amdgcn_mfma_f32_32x32x16_bf16(a, b, c, 0, 0, 0);
}

// swizzled byte offset within a tile of 128-byte rows (GEMM LDS only)
__device__ __forceinline__ int swz(int row, int part) {
  return row * 128 + ((part ^ (row & 7)) << 4);
}

__device__ __forceinline__ u16x8 cast8(const float4* p, float scale) {
  float4 a = p[0], b = p[1];
  u16x8 r;
  r[0] = f2bf(a.x * scale); r[1] = f2bf(a.y * scale);
  r[2] = f2bf(a.z * scale); r[3] = f2bf(a.w * scale);
  r[4] = f2bf(b.x * scale); r[5] = f2bf(b.y * scale);
  r[6] = f2bf(b.z * scale); r[7] = f2bf(b.w * scale);
  return r;
}

// ---------------- one fused cast launch: x, context, 4 weights ----------------
__global__ void cast_all(const float* __restrict__ x, const float* __restrict__ ctx,
                         const float* __restrict__ Wq, const float* __restrict__ Wk,
                         const float* __restrict__ Wv, const float* __restrict__ Wo,
                         u16* __restrict__ xb, u16* __restrict__ cb,
                         u16* __restrict__ wb) {
  int i = blockIdx.x * blockDim.x + threadIdx.x;
  const float* src; u16* dst; int j; float scale = 1.0f;
  if (i < 524288) { src = x; dst = xb; j = i; }
  else if (i < 1048576) { src = ctx; dst = cb; j = i - 524288; }
  else {
    int k = i - 1048576;
    int which = k >> 17; j = k & 131071;
    src = (which == 0) ? Wq : (which == 1) ? Wk : (which == 2) ? Wv : Wo;
    scale = (which < 2) ? QK_SCALE : 1.0f;
    dst = wb + (size_t)which * (NE * KDIM);
  }
  *((u16x8*)dst + j) = cast8((const float4*)src + (size_t)j * 2, scale);
}

// ---------------- fused Q + KV projection GEMM (R7-form: serial, 24KB LDS, 6 blk/CU) ----------------
// blocks [0,512): Q = xb @ Wq^T -> Qb; [512,1536): KV = cb @ [Wk;Wv]^T -> K/V tiled-transposed
__global__ __launch_bounds__(256)
void gemm_qkv(const u16* __restrict__ xb, const u16* __restrict__ cb,
              const u16* __restrict__ wqb, const u16* __restrict__ wkvb,
              u16* __restrict__ Qb, u16* __restrict__ KVb) {
  __shared__ __align__(16) u16 Al[64 * 64];
  __shared__ __align__(16) u16 Bl[128 * 64];
  const int tid = threadIdx.x, w = tid >> 6, l = tid & 63;
  const int l15 = l & 15, l4 = l >> 4;
  const int wm = w >> 1, wn = w & 1;

  const int bid = blockIdx.x;
  const bool isQ = bid < 512;
  const u16* A; const u16* Bm; int mbase, nbase;
  if (isQ) { A = xb; Bm = wqb; nbase = (bid & 7) * 128; mbase = (bid >> 3) * 64; }
  else { int b2 = bid - 512; A = cb; Bm = wkvb; nbase = (b2 & 15) * 128; mbase = (b2 >> 4) * 64; }

  f32x4 acc[2][4] = {};
  const char* Ab = (const char*)(A + (size_t)mbase * KDIM);
  const char* Bb = (const char*)(Bm + (size_t)nbase * KDIM);

  for (int k0 = 0; k0 < KDIM; k0 += 64) {
#pragma unroll
    for (int s = 0; s < 2; ++s) {
      int i = (w * 2 + s) * 64 + l;      // 0..511
      int row = i >> 3, part = i & 7;
      int gofs = row * (KDIM * 2) + k0 * 2 + ((part ^ (row & 7)) << 4);
      gload16(Ab + gofs, (char*)Al + (w * 2 + s) * 1024);
    }
#pragma unroll
    for (int s = 0; s < 4; ++s) {
      int i = (w * 4 + s) * 64 + l;      // 0..1023
      int row = i >> 3, part = i & 7;
      int gofs = row * (KDIM * 2) + k0 * 2 + ((part ^ (row & 7)) << 4);
      gload16(Bb + gofs, (char*)Bl + (w * 4 + s) * 1024);
    }
    __syncthreads();
#pragma unroll
    for (int kc = 0; kc < 2; ++kc) {
      bf16x8 af[2], bfr[4];
#pragma unroll
      for (int mt = 0; mt < 2; ++mt) {
        int r = wm * 32 + mt * 16 + l15;
        af[mt] = *(const bf16x8*)((const char*)Al + swz(r, kc * 4 + l4));
      }
#pragma unroll
      for (int nt = 0; nt < 4; ++nt) {
        int r = wn * 64 + nt * 16 + l15;
        bfr[nt] = *(const bf16x8*)((const char*)Bl + swz(r, kc * 4 + l4));
      }
#pragma unroll
      for (int mt = 0; mt < 2; ++mt)
#pragma unroll
        for (int nt = 0; nt < 4; ++nt)
          acc[mt][nt] = mfma16x16(af[mt], bfr[nt], acc[mt][nt]);
    }
    __syncthreads();
  }

#pragma unroll
  for (int mt = 0; mt < 2; ++mt) {
#pragma unroll
    for (int nt = 0; nt < 4; ++nt) {
      int col = nbase + wn * 64 + nt * 16 + l15;
      int mrow0 = mbase + wm * 32 + mt * 16 + l4 * 4;
#pragma unroll
      for (int r = 0; r < 4; ++r) {
        int m = mrow0 + r;
        float v = acc[mt][nt][r];
        if (isQ) {
          int b = m >> 11, t = m & (NT - 1), h = col >> 6, d = col & (ND - 1);
          Qb[((size_t)(b * NH + h) * NT + t) * ND + d] = f2bf(v);
        } else {
          int b = m >> 11, tc = m & (NTC - 1);
          int h = (col >> 6) & 15, d = col & (ND - 1);
          size_t base = ((size_t)((b * NH + h) * 32 + (tc >> 6))) * 4096;
          if (col < 1024) {  // K layout: [dpart][key][d&7]
            size_t idx = base + (size_t)(d >> 3) * 512 + (size_t)(tc & 63) * 8 + (d & 7);
            KVb[idx] = f2bf(v);
          } else {           // V layout: [keypart][d][key&7], V buffer at +4M elems
            size_t idx = base + (size_t)((tc & 63) >> 3) * 512 + (size_t)d * 8 + (tc & 7);
            KVb[4194304 + idx] = f2bf(v);
          }
        }
      }
    }
  }
}

// ---------------- R8-form double-buffered GEMM loop (for gemm_out only) ----------------
__device__ __forceinline__ void gemm_loop(const char* Ab, const char* Bb,
                                          u16* Al, u16* Bl, int tid,
                                          f32x4 (&acc)[2][4]) {
  const int w = tid >> 6, l = tid & 63;
  const int l15 = l & 15, l4 = l >> 4;
  const int wm = w >> 1, wn = w & 1;

  auto stage = [&](int buf, int k0) {
#pragma unroll
    for (int s = 0; s < 2; ++s) {
      int i = (w * 2 + s) * 64 + l;      // 0..511
      int row = i >> 3, part = i & 7;
      int gofs = row * (KDIM * 2) + k0 * 2 + ((part ^ (row & 7)) << 4);
      gload16(Ab + gofs, (char*)(Al + buf * 4096) + (w * 2 + s) * 1024);
    }
#pragma unroll
    for (int s = 0; s < 4; ++s) {
      int i = (w * 4 + s) * 64 + l;      // 0..1023
      int row = i >> 3, part = i & 7;
      int gofs = row * (KDIM * 2) + k0 * 2 + ((part ^ (row & 7)) << 4);
      gload16(Bb + gofs, (char*)(Bl + buf * 8192) + (w * 4 + s) * 1024);
    }
  };

  stage(0, 0);
  stage(1, 64);

  for (int it = 0; it < 16; ++it) {
    const int cur = it & 1;
    if (it < 15) asm volatile("s_waitcnt vmcnt(6)" ::: "memory");
    else         asm volatile("s_waitcnt vmcnt(0)" ::: "memory");
    __builtin_amdgcn_s_barrier();
    const char* Ac = (const char*)(Al + cur * 4096);
    const char* Bc = (const char*)(Bl + cur * 8192);
#pragma unroll
    for (int kc = 0; kc < 2; ++kc) {
      bf16x8 af[2], bfr[4];
#pragma unroll
      for (int mt = 0; mt < 2; ++mt)
        af[mt] = *(const bf16x8*)(Ac + swz(wm * 32 + mt * 16 + l15, kc * 4 + l4));
#pragma unroll
      for (int nt = 0; nt < 4; ++nt)
        bfr[nt] = *(const bf16x8*)(Bc + swz(wn * 64 + nt * 16 + l15, kc * 4 + l4));
#pragma unroll
      for (int mt = 0; mt < 2; ++mt)
#pragma unroll
        for (int nt = 0; nt < 4; ++nt)
          acc[mt][nt] = mfma16x16(af[mt], bfr[nt], acc[mt][nt]);
    }
    __builtin_amdgcn_s_barrier();
    if (it < 14) stage(cur, (it + 2) * 64);
  }
}

// ---------------- out projection GEMM (R8-form: dbuf + chunk-swizzle) ----------------
__global__ __launch_bounds__(256)
void gemm_out(const u16* __restrict__ A, const u16* __restrict__ Bm,
              float* __restrict__ Cout, const float* __restrict__ bias) {
  __shared__ __align__(16) u16 Al[2][64 * 64];
  __shared__ __align__(16) u16 Bl[2][128 * 64];
  const int tid = threadIdx.x, w = tid >> 6, l = tid & 63;
  const int l15 = l & 15, l4 = l >> 4;
  const int wm = w >> 1, wn = w & 1;

  int bid = blockIdx.x;
  bid = (bid & 7) * 64 + (bid >> 3);    // bijective: 512 = 8*64
  const int mbase = (bid >> 3) * 64, nbase = (bid & 7) * 128;

  f32x4 acc[2][4] = {};
  gemm_loop((const char*)(A + (size_t)mbase * KDIM),
            (const char*)(Bm + (size_t)nbase * KDIM),
            &Al[0][0], &Bl[0][0], tid, acc);

#pragma unroll
  for (int mt = 0; mt < 2; ++mt) {
#pragma unroll
    for (int nt = 0; nt < 4; ++nt) {
      int col = nbase + wn * 64 + nt * 16 + l15;
      int mrow0 = mbase + wm * 32 + mt * 16 + l4 * 4;
#pragma unroll
      for (int r = 0; r < 4; ++r)
        Cout[(size_t)(mrow0 + r) * NE + col] = acc[mt][nt][r] + bias[col];
    }
  }
}

// ---------------- flash attention (R5 verbatim — known-good) ----------------
__global__ __launch_bounds__(128, 2)
void attn_fwd(const u16* __restrict__ Q, const u16* __restrict__ K,
              const u16* __restrict__ Vt, u16* __restrict__ O) {
  __shared__ float Ol[64 * 64];
  __shared__ float Ll[64];
  const int tid = threadIdx.x, wid = tid >> 6, l = tid & 63;
  const int l31 = l & 31, hi = l >> 5;

  int n = blockIdx.x;
  int work = (n & 7) * 128 + (n >> 3);
  const int bh = work >> 5, qx = work & 31;
  const int b = bh >> 4, h = bh & 15;
  const int qbase = qx * 64;

  const char* Kb = (const char*)(K + (size_t)bh * 32 * 4096);
  const char* Vb = (const char*)(Vt + (size_t)bh * 32 * 4096);
  const u16* Qb = Q + (size_t)bh * NT * ND;

  auto kaddr = [&](int t32, int kc) {
    return Kb + (size_t)(t32 >> 1) * 8192 + (size_t)(kc * 2 + hi) * 1024
              + (size_t)((t32 & 1) * 32 + l31) * 16;
  };
  auto vaddr = [&](int t32, int j) {  // j = ks*2 + nt
    return Vb + (size_t)(t32 >> 1) * 8192
              + (size_t)((t32 & 1) * 4 + (j >> 1) * 2 + hi) * 1024
              + (size_t)((j & 1) * 32 + l31) * 16;
  };

  bf16x8 qf[2][4];
#pragma unroll
  for (int qt = 0; qt < 2; ++qt)
#pragma unroll
    for (int kc = 0; kc < 4; ++kc)
      qf[qt][kc] = *(const bf16x8*)(Qb + (size_t)(qbase + qt * 32 + l31) * ND + kc * 16 + hi * 8);

  f32x16 oacc[2][2] = {};
  f32x16 lacc[2] = {};
  f32x16 minit;
#pragma unroll
  for (int r = 0; r < 16; ++r) minit[r] = -FIXED_M;

  const int tbase = wid * 32;

  bf16x8 kfA[4], kfB[4], vf[4];
#pragma unroll
  for (int kc = 0; kc < 4; ++kc) kfA[kc] = *(const bf16x8*)kaddr(tbase, kc);

  for (int it2 = 0; it2 < 16; ++it2) {
    const int tA = tbase + it2 * 2, tB = tA + 1;

    // ---- iter A (uses kfA, prefetches kfB = tB) ----
#pragma unroll
    for (int j = 0; j < 4; ++j) vf[j] = *(const bf16x8*)vaddr(tA, j);
#pragma unroll
    for (int kc = 0; kc < 4; ++kc) kfB[kc] = *(const bf16x8*)kaddr(tB, kc);
#pragma unroll
    for (int qt = 0; qt < 2; ++qt) {
      f32x16 sv = minit;
#pragma unroll
      for (int kc = 0; kc < 4; ++kc) sv = mfma32x32(kfA[kc], qf[qt][kc], sv);
#pragma unroll
      for (int r = 0; r < 16; ++r) { sv[r] = fexp2(sv[r]); lacc[qt][r] += sv[r]; }
      bf16x8 pa0, pa1;
      {
        u32 a1 = cvtpk(sv[0], sv[1]), b1 = cvtpk(sv[4], sv[5]);
        u32 a2 = cvtpk(sv[2], sv[3]), b2 = cvtpk(sv[6], sv[7]);
        plswap(a1, b1); plswap(a2, b2);
        u32 a3 = cvtpk(sv[8], sv[9]), b3 = cvtpk(sv[12], sv[13]);
        u32 a4 = cvtpk(sv[10], sv[11]), b4 = cvtpk(sv[14], sv[15]);
        plswap(a3, b3); plswap(a4, b4);
        union { u32 u[4]; bf16x8 v; } ua, ub;
        ua.u[0] = a1; ua.u[1] = a2; ua.u[2] = b1; ua.u[3] = b2;
        ub.u[0] = a3; ub.u[1] = a4; ub.u[2] = b3; ub.u[3] = b4;
        pa0 = ua.v; pa1 = ub.v;
      }
      oacc[qt][0] = mfma32x32(pa0, vf[0], oacc[qt][0]);
      oacc[qt][1] = mfma32x32(pa0, vf[1], oacc[qt][1]);
      oacc[qt][0] = mfma32x32(pa1, vf[2], oacc[qt][0]);
      oacc[qt][1] = mfma32x32(pa1, vf[3], oacc[qt][1]);
    }

    // ---- iter B (uses kfB, prefetches kfA = tB+1) ----
#pragma unroll
    for (int j = 0; j < 4; ++j) vf[j] = *(const bf16x8*)vaddr(tB, j);
#pragma unroll
    for (int kc = 0; kc < 4; ++kc) kfA[kc] = *(const bf16x8*)kaddr(tB + 1, kc);
#pragma unroll
    for (int qt = 0; qt < 2; ++qt) {
      f32x16 sv = minit;
#pragma unroll
      for (int kc = 0; kc < 4; ++kc) sv = mfma32x32(kfB[kc], qf[qt][kc], sv);
#pragma unroll
      for (int r = 0; r < 16; ++r) { sv[r] = fexp2(sv[r]); lacc[qt][r] += sv[r]; }
      bf16x8 pa0, pa1;
      {
        u32 a1 = cvtpk(sv[0], sv[1]), b1 = cvtpk(sv[4], sv[5]);
        u32 a2 = cvtpk(sv[2], sv[3]), b2 = cvtpk(sv[6], sv[7]);
        plswap(a1, b1); plswap(a2, b2);
        u32 a3 = cvtpk(sv[8], sv[9]), b3 = cvtpk(sv[12], sv[13]);
        u32 a4 = cvtpk(sv[10], sv[11]), b4 = cvtpk(sv[14], sv[15]);
        plswap(a3, b3); plswap(a4, b4);
        union { u32 u[4]; bf16x8 v; } ua, ub;
        ua.u[0] = a1; ua.u[1] = a2; ua.u[2] = b1; ua.u[3] = b2;
        ub.u[0] = a3; ub.u[1] = a4; ub.u[2] = b3; ub.u[3] = b4;
        pa0 = ua.v; pa1 = ub.v;
      }
      oacc[qt][0] = mfma32x32(pa0, vf[0], oacc[qt][0]);
      oacc[qt][1] = mfma32x32(pa0, vf[1], oacc[qt][1]);
      oacc[qt][0] = mfma32x32(pa1, vf[2], oacc[qt][0]);
      oacc[qt][1] = mfma32x32(pa1, vf[3], oacc[qt][1]);
    }
  }

  float lsum[2];
#pragma unroll
  for (int qt = 0; qt < 2; ++qt) {
    f32x16 t = lacc[qt];
#pragma unroll
    for (int s = 8; s >= 1; s >>= 1)
#pragma unroll
      for (int r = 0; r < s; ++r) t[r] += t[r + s];
    lsum[qt] = t[0] + __shfl_xor(t[0], 32);
  }

  if (wid == 1) {
#pragma unroll
    for (int qt = 0; qt < 2; ++qt) {
#pragma unroll
      for (int r = 0; r < 16; ++r) {
        int crow = (r & 3) + 8 * (r >> 2) + 4 * hi;
        Ol[(qt * 32 + crow) * 64 + l31] = oacc[qt][0][r];
        Ol[(qt * 32 + crow) * 64 + 32 + l31] = oacc[qt][1][r];
      }
      if (!hi) Ll[qt * 32 + l31] = lsum[qt];
    }
  }
  __syncthreads();
  if (wid == 0) {
#pragma unroll
    for (int qt = 0; qt < 2; ++qt) {
      float inv = 1.0f / (lsum[qt] + Ll[qt * 32 + l31]);
#pragma unroll
      for (int r = 0; r < 16; ++r) {
        int crow = (r & 3) + 8 * (r >> 2) + 4 * hi;
        float ir = __shfl(inv, crow);
        int t = qbase + qt * 32 + crow;
        size_t rowo = (size_t)(b * NT + t) * NE + h * 64 + l31;
        O[rowo] = f2bf((oacc[qt][0][r] + Ol[(qt * 32 + crow) * 64 + l31]) * ir);
        O[rowo + 32] = f2bf((oacc[qt][1][r] + Ol[(qt * 32 + crow) * 64 + 32 + l31]) * ir);
      }
    }
  }
}

// ---------------- launch ----------------
extern "C" void kernel_launch(void* const* d_in, const int* in_sizes, int n_in,
                              void* d_out, int out_size, void* d_ws, size_t ws_size,
                              hipStream_t stream) {
  const float* x   = (const float*)d_in[0];
  const float* ctx = (const float*)d_in[1];
  const float* Wq  = (const float*)d_in[2];
  const float* Wk  = (const float*)d_in[3];
  const float* Wv  = (const float*)d_in[4];
  const float* Wo  = (const float*)d_in[5];
  const float* bo  = (const float*)d_in[6];
  float* out = (float*)d_out;
  char* ws = (char*)d_ws;

  u16* xb  = (u16*)(ws);                       // 8 MB  x  bf16 [4096][1024]
  u16* cb  = (u16*)(ws + (8u  << 20));         // 8 MB  ctx bf16 [4096][1024]
  u16* wqb = (u16*)(ws + (16u << 20));         // 2 MB  Wq*s  (4 weights contiguous)
  u16* wkb = (u16*)(ws + (18u << 20));         // 2 MB  Wk*s (Wv contiguous after)
  u16* wob = (u16*)(ws + (22u << 20));         // 2 MB  Wo
  u16* Qb  = (u16*)(ws + (24u << 20));         // 8 MB  Q  [bh][t][64]
  u16* Kb  = (u16*)(ws + (32u << 20));         // 8 MB  K  tiled-transposed (V contiguous)
  u16* Vtb = (u16*)(ws + (40u << 20));         // 8 MB  V  tiled-transposed
  u16* Ob  = (u16*)(ws + (48u << 20));         // 8 MB  O  [token][1024]

  cast_all<<<6144, 256, 0, stream>>>(x, ctx, Wq, Wk, Wv, Wo, xb, cb, wqb);
  gemm_qkv<<<1536, 256, 0, stream>>>(xb, cb, wqb, wkb, Qb, Kb);
  attn_fwd<<<1024, 128, 0, stream>>>(Qb, Kb, Vtb, Ob);
  gemm_out<<<512, 256, 0, stream>>>(Ob, wob, out, bo);
}